// Round 15
// baseline (501.999 us; speedup 1.0000x reference)
//
#include <hip/hip_runtime.h>

#define TT   1024
#define DIN  8
#define RING 256          // h1 ring slots (32 KB LDS); backpressure at RING-16

typedef float f32x2 __attribute__((ext_vector_type(2)));

// sigma(x) = 1 / (1 + exp2(-x*log2e))
__device__ __forceinline__ float fsig(float x) {
    float e = __builtin_amdgcn_exp2f(-1.4426950408889634f * x);
    return __builtin_amdgcn_rcpf(1.0f + e);
}
// tanh(x) = 2*sigma(2x) - 1
__device__ __forceinline__ float ftanh_(float x) {
    float e = __builtin_amdgcn_exp2f(-2.8853900817779268f * x);
    return 2.0f * __builtin_amdgcn_rcpf(1.0f + e) - 1.0f;
}
// DPP pair swap (lane 2k <-> 2k+1)
template<int CTRL>
__device__ __forceinline__ float dppf(float v) {
    return __uint_as_float((unsigned)__builtin_amdgcn_update_dpp(
        0, (int)__float_as_uint(v), CTRL, 0xF, 0xF, true));
}
// packed 2-wide FMA -> v_pk_fma_f32
__device__ __forceinline__ f32x2 pkfma(f32x2 a, f32x2 b, f32x2 c) {
    return __builtin_elementwise_fma(a, b, c);
}

// ============================ kernel 1: recurrence ============================
// 2 DECOUPLED waves per batch element (block=128, grid=256). No s_barrier in
// the main loops. Wave0 = whole layer 1 (2 gate rows/lane, 80 wts; R2-verified
// pair layout: even lane (i,g), odd (f,o) of unit j=l>>1). Wave1 = whole
// layer 2 (2 rows/lane, 128 wts). Each wave's h self-broadcast is a SAME-WAVE
// LDS round trip (write 32 -> in-order DS queue -> 8 uniform b128 reads): no
// inter-wave sync needed for its own recurrence. h1 flows wave0->wave1 via a
// 256-slot LDS ring + monotonic progress counters (volatile LDS ints):
// producer drains lgkmcnt(0) before bumping prog, consumer caches prog and
// re-polls only when behind (steady state: wave0 runs ahead -> no polls).
// Backpressure: wave0 waits if > RING-16 ahead. h2(t) fire-and-forget to
// out[b][t][0:32] scratch; kernel 2 expands to the 80-col linear.
__global__ void __launch_bounds__(128, 1)
lstm_rec(const float* __restrict__ x,
         const float* __restrict__ Wih1, const float* __restrict__ Whh1,
         const float* __restrict__ bih1, const float* __restrict__ bhh1,
         const float* __restrict__ Wih2, const float* __restrict__ Whh2,
         const float* __restrict__ bih2, const float* __restrict__ bhh2,
         float* __restrict__ out)
{
    const int tid = threadIdx.x;
    const int wv  = tid >> 6;          // 0 = layer1, 1 = layer2
    const int l   = tid & 63;
    const int q   = l & 1;
    const int j   = l >> 1;            // hidden unit 0..31
    const int b   = blockIdx.x;
    const int r0  = q ? (32 + j) : j;          // i | f
    const int r1  = q ? (96 + j) : (64 + j);   // g | o

    __shared__ float ring[RING][32];   // h1 history ring
    __shared__ float hs[2][32];        // [0]=h1 self, [1]=h2 self
    __shared__ int   prog[2];          // [0]=wave0 steps done, [1]=wave1
    if (tid < 64) ((float*)hs)[tid] = 0.f;
    if (tid < 2)  prog[tid] = 0;
    __syncthreads();                   // init visible (only barrier)

    volatile int* vp0 = &prog[0];
    volatile int* vp1 = &prog[1];

    if (wv == 0) {
        // ================= wave0: layer 1 =================
        f32x2 wh0[16], wh1[16], wx0[4], wx1[4];
#pragma unroll
        for (int k = 0; k < 16; ++k) {
            wh0[k] = reinterpret_cast<const f32x2*>(Whh1 + r0*32)[k];
            wh1[k] = reinterpret_cast<const f32x2*>(Whh1 + r1*32)[k];
        }
#pragma unroll
        for (int k = 0; k < 4; ++k) {
            wx0[k] = reinterpret_cast<const f32x2*>(Wih1 + r0*DIN)[k];
            wx1[k] = reinterpret_cast<const f32x2*>(Wih1 + r1*DIN)[k];
        }
        const float b0 = bih1[r0] + bhh1[r0];
        const float b1 = bih1[r1] + bhh1[r1];
        float c1 = 0.f;
        const float* __restrict__ xb = x + (size_t)b * (TT*DIN);
        float4 xa = reinterpret_cast<const float4*>(xb)[0];
        float4 xc = reinterpret_cast<const float4*>(xb)[1];
        int xoff = DIN;
        int w1seen = 0;

#pragma unroll 1
        for (int t = 0; t < TT; ++t) {
            if (t - w1seen >= RING - 16) {          // backpressure (rare)
                do { __builtin_amdgcn_s_sleep(2); w1seen = *vp1; }
                while (t - w1seen >= RING - 16);
            }
            asm volatile("" ::: "memory");          // no read hoisting past poll

            f32x2 a0 = {b0, 0.f}, a1 = {0.f, 0.f};
            f32x2 g0 = {b1, 0.f}, g1 = {0.f, 0.f};
#pragma unroll
            for (int qq = 0; qq < 8; ++qq) {        // h1(t-1) self, uniform b128
                float4 v = reinterpret_cast<const float4*>(&hs[0][0])[qq];
                f32x2 lo = {v.x, v.y}, hi = {v.z, v.w};
                a0 = pkfma(wh0[2*qq],   lo, a0);
                a1 = pkfma(wh0[2*qq+1], hi, a1);
                g0 = pkfma(wh1[2*qq],   lo, g0);
                g1 = pkfma(wh1[2*qq+1], hi, g1);
            }
            f32x2 xp0 = {xa.x, xa.y}, xp1 = {xa.z, xa.w};
            f32x2 xp2 = {xc.x, xc.y}, xp3 = {xc.z, xc.w};
            a0 = pkfma(wx0[0], xp0, a0);  a1 = pkfma(wx0[1], xp1, a1);
            a0 = pkfma(wx0[2], xp2, a0);  a1 = pkfma(wx0[3], xp3, a1);
            g0 = pkfma(wx1[0], xp0, g0);  g1 = pkfma(wx1[1], xp1, g1);
            g0 = pkfma(wx1[2], xp2, g0);  g1 = pkfma(wx1[3], xp3, g1);
            xa = reinterpret_cast<const float4*>(xb + xoff)[0];   // prefetch
            xc = reinterpret_cast<const float4*>(xb + xoff)[1];
            xoff = (xoff + DIN > (TT-1)*DIN) ? (TT-1)*DIN : (xoff + DIN);

            float p0 = (a0.x + a0.y) + (a1.x + a1.y);
            float p1 = (g0.x + g0.y) + (g1.x + g1.y);
            float A  = fsig(p0);                    // sig(i) even | sig(f) odd
            float uu = q ? p1 : (p1 + p1);
            float S  = fsig(uu);
            float Bv = q ? S : (S + S - 1.0f);      // tanh(g) even | sig(o) odd
            float An = dppf<0xB1>(A), Bn = dppf<0xB1>(Bv);
            float si = q ? An : A,  sf = q ? A  : An;
            float tg = q ? Bn : Bv, so = q ? Bv : Bn;
            c1 = sf * c1 + si * tg;
            float h1v = so * ftanh_(c1);            // both pair lanes
            if (!q) { hs[0][j] = h1v; ring[t & (RING-1)][j] = h1v; }
            asm volatile("s_waitcnt lgkmcnt(0)" ::: "memory");  // data before flag
            if (l == 0) *vp0 = t + 1;               // publish progress
        }
    } else {
        // ================= wave1: layer 2 =================
        f32x2 u0w[16], u1w[16], v0w[16], v1w[16];
#pragma unroll
        for (int k = 0; k < 16; ++k) {
            u0w[k] = reinterpret_cast<const f32x2*>(Whh2 + r0*32)[k];  // x h2
            u1w[k] = reinterpret_cast<const f32x2*>(Whh2 + r1*32)[k];
            v0w[k] = reinterpret_cast<const f32x2*>(Wih2 + r0*32)[k];  // x h1
            v1w[k] = reinterpret_cast<const f32x2*>(Wih2 + r1*32)[k];
        }
        const float b0 = bih2[r0] + bhh2[r0];
        const float b1 = bih2[r1] + bhh2[r1];
        float c2 = 0.f;
        float* __restrict__ outb = out + (size_t)b * (TT*80);
        int o2 = 0;
        int w0seen = 0;

#pragma unroll 1
        for (int t = 0; t < TT; ++t) {
            if (w0seen < t + 1) {                   // poll producer (rare)
                do { __builtin_amdgcn_s_sleep(1); w0seen = *vp0; }
                while (w0seen < t + 1);
            }
            asm volatile("" ::: "memory");          // no read hoisting past poll

            f32x2 a0 = {b0, 0.f}, a1 = {0.f, 0.f};
            f32x2 g0 = {b1, 0.f}, g1 = {0.f, 0.f};
            const float* rp = &ring[t & (RING-1)][0];
#pragma unroll
            for (int qq = 0; qq < 8; ++qq) {        // h1(t) from ring
                float4 v = reinterpret_cast<const float4*>(rp)[qq];
                f32x2 lo = {v.x, v.y}, hi = {v.z, v.w};
                a0 = pkfma(v0w[2*qq],   lo, a0);
                a1 = pkfma(v0w[2*qq+1], hi, a1);
                g0 = pkfma(v1w[2*qq],   lo, g0);
                g1 = pkfma(v1w[2*qq+1], hi, g1);
            }
#pragma unroll
            for (int qq = 0; qq < 8; ++qq) {        // h2(t-1) self
                float4 v = reinterpret_cast<const float4*>(&hs[1][0])[qq];
                f32x2 lo = {v.x, v.y}, hi = {v.z, v.w};
                a0 = pkfma(u0w[2*qq],   lo, a0);
                a1 = pkfma(u0w[2*qq+1], hi, a1);
                g0 = pkfma(u1w[2*qq],   lo, g0);
                g1 = pkfma(u1w[2*qq+1], hi, g1);
            }
            float p0 = (a0.x + a0.y) + (a1.x + a1.y);
            float p1 = (g0.x + g0.y) + (g1.x + g1.y);
            float A  = fsig(p0);
            float uu = q ? p1 : (p1 + p1);
            float S  = fsig(uu);
            float Bv = q ? S : (S + S - 1.0f);
            float An = dppf<0xB1>(A), Bn = dppf<0xB1>(Bv);
            float si = q ? An : A,  sf = q ? A  : An;
            float tg = q ? Bn : Bv, so = q ? Bv : Bn;
            c2 = sf * c2 + si * tg;
            float h2v = so * ftanh_(c2);
            if (!q) { hs[1][j] = h2v; outb[o2 + j] = h2v; }   // scratch store
            o2 += 80;
            if ((t & 15) == 15) {                   // progress every 16 steps
                asm volatile("s_waitcnt lgkmcnt(0)" ::: "memory");
                if (l == 0) *vp1 = t + 1;
            }
        }
    }
}

// ============================ kernel 2: out linear ============================
// out[row][0:80] = h2[row] @ Wlin^T + blin, h2 scratch = out[row][0:32].
// Unchanged from round 11 (verified; ~17 us).
__global__ void __launch_bounds__(256, 4)
out_lin(const float* __restrict__ Wlin, const float* __restrict__ blin,
        float* __restrict__ out, int ntiles)
{
    __shared__ float wl[80][36];
    __shared__ float bl[80];
    __shared__ float ht[16][36];
    const int tid = threadIdx.x;

#pragma unroll 1
    for (int i = tid; i < 640; i += 256) {          // 80 rows x 8 float4
        const int cc = i >> 3, qq = i & 7;
        float4 v = reinterpret_cast<const float4*>(Wlin)[i];
        *reinterpret_cast<float4*>(&wl[cc][qq*4]) = v;
    }
    if (tid < 80) bl[tid] = blin[tid];
    __syncthreads();

    const int row = tid >> 4;   // 0..15
    const int cl  = tid & 15;   // 0..15

#pragma unroll 1
    for (int tile = blockIdx.x; tile < ntiles; tile += gridDim.x) {
        const size_t base = (size_t)tile * 16;
        if (tid < 128) {                            // stage 16 rows of h2
            const int r = tid >> 3, qq = tid & 7;
            float4 v = *reinterpret_cast<const float4*>(out + (base + r)*80 + qq*4);
            *reinterpret_cast<float4*>(&ht[r][qq*4]) = v;
        }
        __syncthreads();

        float hr[32];
#pragma unroll
        for (int jj = 0; jj < 8; ++jj) {
            float4 v = *reinterpret_cast<const float4*>(&ht[row][jj*4]);
            hr[4*jj]=v.x; hr[4*jj+1]=v.y; hr[4*jj+2]=v.z; hr[4*jj+3]=v.w;
        }
        float res[5];
#pragma unroll
        for (int cj = 0; cj < 5; ++cj) {
            const int cc = cl + 16*cj;
            float a0 = bl[cc], a1 = 0.f, a2 = 0.f, a3 = 0.f;
#pragma unroll
            for (int k = 0; k < 32; k += 4) {
                a0 += wl[cc][k]  *hr[k];   a1 += wl[cc][k+1]*hr[k+1];
                a2 += wl[cc][k+2]*hr[k+2]; a3 += wl[cc][k+3]*hr[k+3];
            }
            res[cj] = (a0 + a1) + (a2 + a3);
        }
        __syncthreads();   // ht reads complete before next tile's staging
#pragma unroll
        for (int cj = 0; cj < 5; ++cj)
            out[(base + row)*80 + cl + 16*cj] = res[cj];
    }
}

extern "C" void kernel_launch(void* const* d_in, const int* in_sizes, int n_in,
                              void* d_out, int out_size, void* d_ws, size_t ws_size,
                              hipStream_t stream) {
    const float* x    = (const float*)d_in[0];
    const float* Wih1 = (const float*)d_in[1];
    const float* Whh1 = (const float*)d_in[2];
    const float* bih1 = (const float*)d_in[3];
    const float* bhh1 = (const float*)d_in[4];
    const float* Wih2 = (const float*)d_in[5];
    const float* Whh2 = (const float*)d_in[6];
    const float* bih2 = (const float*)d_in[7];
    const float* bhh2 = (const float*)d_in[8];
    const float* Wlin = (const float*)d_in[9];
    const float* blin = (const float*)d_in[10];

    const int B = in_sizes[0] / (TT * DIN);   // 256
    const int ntiles = (B * TT) / 16;         // 16384

    hipLaunchKernelGGL(lstm_rec, dim3(B), dim3(128), 0, stream,
                       x, Wih1, Whh1, bih1, bhh1,
                       Wih2, Whh2, bih2, bhh2,
                       (float*)d_out);
    hipLaunchKernelGGL(out_lin, dim3(2048), dim3(256), 0, stream,
                       Wlin, blin, (float*)d_out, ntiles);
}